// Round 6
// baseline (51.185 us; speedup 1.0000x reference)
//
#include <hip/hip_runtime.h>

#define N_MEM 8
#define BSZ   64
#define DK    256
#define DV    256

typedef float f32x4 __attribute__((ext_vector_type(4)));

// ---------------------------------------------------------------------------
// 2048 blocks x 256 threads. Block = (n, b, k-chunk of 64 rows).
// new_state[k][v] = lam * state[k][v] + (rho*alpha) * key[k] * value[v]
// readout[v]     += query[k] * new_state[k][v]
//
// Cached loads (states stays partially L3-resident across graph replays),
// non-temporal stores (write stream should not evict the read stream).
// Readout is accumulated straight into out_read with device-scope atomics
// (out_read is zeroed by a hipMemsetAsync issued before this kernel), which
// removes the dependent reduce dispatch entirely.
// ---------------------------------------------------------------------------
__global__ __launch_bounds__(256) void mom_kernel_fine(
    const float* __restrict__ states,   // [N, B, DK, DV]
    const float* __restrict__ key,      // [B, DK]
    const float* __restrict__ value,    // [B, DV]
    const float* __restrict__ alpha,    // [B, 1]
    const float* __restrict__ rho,      // [B, N]
    const float* __restrict__ lam,      // [B, N]
    const float* __restrict__ query,    // [B, DK]
    float* __restrict__ out_states,     // [N, B, DK, DV]
    float* __restrict__ out_read)       // [N, B, DV]
{
    const int bid4  = blockIdx.x;        // (n*B + b)*4 + chunk
    const int group = bid4 >> 2;         // n*B + b
    const int chunk = bid4 & 3;          // which 64-row k-chunk
    const int n     = group >> 6;
    const int b     = group & 63;
    const int t     = threadIdx.x;

    __shared__ float s_key[64];          // this chunk's 64 key entries
    __shared__ float s_q[64];            // this chunk's 64 query entries
    __shared__ f32x4 s_val4[DV / 4];     // full value row
    __shared__ f32x4 s_red[256];

    if (t < 64) {
        const int kg = chunk * 64 + t;
        s_key[t] = key[b * DK + kg];
        s_q[t]   = query[b * DK + kg];
    } else if (t < 128) {
        const int v4 = t - 64;
        s_val4[v4] = reinterpret_cast<const f32x4*>(value + (size_t)b * DV)[v4];
    }
    const float lam_s = lam[b * N_MEM + n];
    const float w_s   = rho[b * N_MEM + n] * alpha[b];
    __syncthreads();

    // flat float4 index within chunk: idx = t + it*256
    //   v4 = idx & 63 = t & 63 (const);  k_local = (t>>6) + it*4
    const int   v4  = t & 63;
    const f32x4 val = s_val4[v4];
    const int   k0  = t >> 6;

    const size_t base = (size_t)group * (DK * DV) + (size_t)chunk * (64 * DV);
    const f32x4* __restrict__ sp = reinterpret_cast<const f32x4*>(states + base);
    f32x4*       __restrict__ op = reinterpret_cast<f32x4*>(out_states + base);

    f32x4 racc = (f32x4)(0.f);

#pragma unroll
    for (int half = 0; half < 2; ++half) {
        f32x4 s[8];
#pragma unroll
        for (int j = 0; j < 8; ++j)
            s[j] = sp[t + (half * 8 + j) * 256];

        float kw8[8], qv8[8];
#pragma unroll
        for (int j = 0; j < 8; ++j) {
            const int it = half * 8 + j;
            kw8[j] = w_s * s_key[k0 + it * 4];
            qv8[j] = s_q[k0 + it * 4];
        }

#pragma unroll
        for (int j = 0; j < 8; ++j) {
            const int it = half * 8 + j;
            const f32x4 ns = lam_s * s[j] + kw8[j] * val;
            __builtin_nontemporal_store(ns, &op[t + it * 256]);
            racc += qv8[j] * ns;
        }
    }

    // Reduce the 4 k-row-groups within the block, then accumulate the
    // 256-float partial into out_read with device-scope atomics.
    s_red[t] = racc;
    __syncthreads();
    if (t < 64) {
        f32x4 acc = s_red[t];
#pragma unroll
        for (int g = 1; g < 4; ++g)
            acc += s_red[t + g * 64];
        float* dst = out_read + (size_t)group * DV + t * 4;
        atomicAdd(dst + 0, acc.x);
        atomicAdd(dst + 1, acc.y);
        atomicAdd(dst + 2, acc.z);
        atomicAdd(dst + 3, acc.w);
    }
}

extern "C" void kernel_launch(void* const* d_in, const int* in_sizes, int n_in,
                              void* d_out, int out_size, void* d_ws, size_t ws_size,
                              hipStream_t stream) {
    const float* states = (const float*)d_in[0];
    const float* key    = (const float*)d_in[1];
    const float* value  = (const float*)d_in[2];
    const float* alpha  = (const float*)d_in[3];
    const float* rho    = (const float*)d_in[4];
    const float* lam    = (const float*)d_in[5];
    const float* query  = (const float*)d_in[6];

    float* out_states = (float*)d_out;                               // N*B*DK*DV
    float* out_read   = out_states + (size_t)N_MEM * BSZ * DK * DV;  // N*B*DV

    // Zero the readout buffer (atomics accumulate into it). Tiny (512 KB),
    // independent of the heavy kernel, graph-capturable.
    hipMemsetAsync(out_read, 0, (size_t)N_MEM * BSZ * DV * sizeof(float), stream);

    mom_kernel_fine<<<dim3(2048), dim3(256), 0, stream>>>(
        states, key, value, alpha, rho, lam, query, out_states, out_read);
}

// Round 7
// 44.987 us; speedup vs baseline: 1.1378x; 1.1378x over previous
//
#include <hip/hip_runtime.h>

#define N_MEM 8
#define BSZ   64
#define DK    256
#define DV    256

typedef float f32x4 __attribute__((ext_vector_type(4)));

// ---------------------------------------------------------------------------
// 2048 blocks x 256 threads. Block = (group = n*B+b, v-chunk of 64 columns).
// Each block owns ALL k rows of its 64-column stripe, so the readout
//   r[v] = sum_k q[k] * ns[k][v]
// is fully block-local: single kernel, no workspace, no atomics.
//
// new_state[k][v] = lam * state[k][v] + (rho*alpha) * key[k] * value[v]
//
// Access pattern: per wave-load, 4 rows x 256 B contiguous segments at 1 KB
// stride (16 lanes x float4 per row segment). Stripes are 256 B aligned so
// no L2 line is shared across blocks -> no over-fetch, no partial-line
// writes. Cached loads keep `states` partially L3-resident across replays;
// NT stores keep the write stream from evicting it.
// ---------------------------------------------------------------------------
__global__ __launch_bounds__(256) void mom_kernel_vstripe(
    const float* __restrict__ states,   // [N, B, DK, DV]
    const float* __restrict__ key,      // [B, DK]
    const float* __restrict__ value,    // [B, DV]
    const float* __restrict__ alpha,    // [B, 1]
    const float* __restrict__ rho,      // [B, N]
    const float* __restrict__ lam,      // [B, N]
    const float* __restrict__ query,    // [B, DK]
    float* __restrict__ out_states,     // [N, B, DK, DV]
    float* __restrict__ out_read)       // [N, B, DV]
{
    const int bid    = blockIdx.x;       // group*4 + vchunk
    const int group  = bid >> 2;         // n*B + b
    const int vchunk = bid & 3;          // which 64-column stripe
    const int n      = group >> 6;
    const int b      = group & 63;
    const int t      = threadIdx.x;

    __shared__ float s_key[DK];          // full key row
    __shared__ float s_q[DK];            // full query row
    __shared__ f32x4 s_val4[16];         // this stripe's 64 value entries
    __shared__ f32x4 s_red[256];

    s_key[t] = key[b * DK + t];
    s_q[t]   = query[b * DK + t];
    if (t < 16)
        s_val4[t] = reinterpret_cast<const f32x4*>(value + (size_t)b * DV + vchunk * 64)[t];
    const float lam_s = lam[b * N_MEM + n];
    const float w_s   = rho[b * N_MEM + n] * alpha[b];
    __syncthreads();

    // Thread t handles column-float4 (t & 15) of the stripe, rows
    // k = (t>>4) + it*16 for it = 0..15.
    const f32x4 val = s_val4[t & 15];
    const int   kr  = t >> 4;

    // float4 address: C + it*1024 where row stride = 64 float4s.
    const size_t C = (size_t)group * (DK * DV / 4) + vchunk * 16 + (t & 15)
                   + (size_t)kr * 64;
    const f32x4* __restrict__ sp = reinterpret_cast<const f32x4*>(states) + C;
    f32x4*       __restrict__ op = reinterpret_cast<f32x4*>(out_states) + C;

    f32x4 racc = (f32x4)(0.f);

#pragma unroll
    for (int half = 0; half < 2; ++half) {
        // Phase 1: 8 global loads back-to-back.
        f32x4 s[8];
#pragma unroll
        for (int j = 0; j < 8; ++j)
            s[j] = sp[(half * 8 + j) * 1024];

        // Phase 2: coefficient LDS reads (wave-broadcast) overlap vmem wait.
        float kw8[8], qv8[8];
#pragma unroll
        for (int j = 0; j < 8; ++j) {
            const int k = kr + (half * 8 + j) * 16;
            kw8[j] = w_s * s_key[k];
            qv8[j] = s_q[k];
        }

        // Phase 3: fused FMA + NT store + readout accumulate.
#pragma unroll
        for (int j = 0; j < 8; ++j) {
            const f32x4 ns = lam_s * s[j] + kw8[j] * val;
            __builtin_nontemporal_store(ns, &op[(half * 8 + j) * 1024]);
            racc += qv8[j] * ns;
        }
    }

    // Block-local readout reduce: 16 threads share each column-float4.
    s_red[t] = racc;
    __syncthreads();
    if (t < 16) {
        f32x4 acc = s_red[t];
#pragma unroll
        for (int g = 1; g < 16; ++g)
            acc += s_red[t + g * 16];
        reinterpret_cast<f32x4*>(out_read + (size_t)group * DV + vchunk * 64)[t] = acc;
    }
}

extern "C" void kernel_launch(void* const* d_in, const int* in_sizes, int n_in,
                              void* d_out, int out_size, void* d_ws, size_t ws_size,
                              hipStream_t stream) {
    const float* states = (const float*)d_in[0];
    const float* key    = (const float*)d_in[1];
    const float* value  = (const float*)d_in[2];
    const float* alpha  = (const float*)d_in[3];
    const float* rho    = (const float*)d_in[4];
    const float* lam    = (const float*)d_in[5];
    const float* query  = (const float*)d_in[6];

    float* out_states = (float*)d_out;                               // N*B*DK*DV
    float* out_read   = out_states + (size_t)N_MEM * BSZ * DK * DV;  // N*B*DV

    mom_kernel_vstripe<<<dim3(N_MEM * BSZ * 4), dim3(256), 0, stream>>>(
        states, key, value, alpha, rho, lam, query, out_states, out_read);
}